// Round 1
// baseline (988.355 us; speedup 1.0000x reference)
//
#include <hip/hip_runtime.h>

// SimplifiedAttention on MI355X (gfx950)
//   Qn = l2norm(q, dim=-1); Kn = l2norm(k, dim=-1)
//   W  = Qn @ Kn^T   [4, 4096, 4096]  (output 1)
//   O  = W  @ v      [4, 4096, 1024]  (output 0)
// d_out = [O | W] fp32. Compute in bf16 MFMA (fp32 accum); no fp32 MFMA on CDNA4.

#define SEQ 4096
#define EMB 1024
#define NBATCH 4

typedef __attribute__((ext_vector_type(8))) __bf16 bf16x8;
typedef __attribute__((ext_vector_type(4))) float f32x4;

__device__ __forceinline__ unsigned short f2bf(float f) {
    // round-to-nearest-even fp32 -> bf16
    unsigned int u = __builtin_bit_cast(unsigned int, f);
    u += 0x7FFFu + ((u >> 16) & 1u);
    return (unsigned short)(u >> 16);
}

__device__ __forceinline__ bf16x8 ld_bf16x8(const unsigned short* p) {
    int4 v = *(const int4*)p;  // 16 B LDS read (ds_read_b128)
    return __builtin_bit_cast(bf16x8, v);
}

// One block (256 threads) per row of 1024 floats: L2-normalize, store bf16.
__global__ __launch_bounds__(256) void norm_rows_kernel(const float* __restrict__ src,
                                                        unsigned short* __restrict__ dst) {
    int row = blockIdx.x;
    int t = threadIdx.x;
    float4 v = *(const float4*)(src + (size_t)row * EMB + t * 4);
    float ss = v.x * v.x + v.y * v.y + v.z * v.z + v.w * v.w;
#pragma unroll
    for (int off = 32; off > 0; off >>= 1) ss += __shfl_down(ss, off, 64);
    __shared__ float red[4];
    if ((t & 63) == 0) red[t >> 6] = ss;
    __syncthreads();
    float tot = red[0] + red[1] + red[2] + red[3];
    float scale = 1.0f / fmaxf(sqrtf(tot), 1e-12f);  // F.normalize eps
    ushort4 o;
    o.x = f2bf(v.x * scale);
    o.y = f2bf(v.y * scale);
    o.z = f2bf(v.z * scale);
    o.w = f2bf(v.w * scale);
    *(ushort4*)(dst + (size_t)row * EMB + t * 4) = o;
}

// V [b][j][d] fp32 -> Vt [b][d][j] bf16, 64x64 LDS tiles, coalesced both sides.
__global__ __launch_bounds__(256) void transpose_v_kernel(const float* __restrict__ v,
                                                          unsigned short* __restrict__ vt) {
    __shared__ __align__(16) unsigned short T[64][68];  // +4 pad breaks bank stride
    int b = blockIdx.z;
    int j0 = blockIdx.x * 64;
    int d0 = blockIdx.y * 64;
    const float* vb = v + (size_t)b * SEQ * EMB;
    unsigned short* vtb = vt + (size_t)b * (size_t)EMB * SEQ;
    int t = threadIdx.x;
#pragma unroll
    for (int i = 0; i < 4; i++) {
        int lin = t + i * 256;
        int j = lin >> 4;
        int dseg = lin & 15;
        float4 x = *(const float4*)(vb + (size_t)(j0 + j) * EMB + d0 + dseg * 4);
        ushort4 o;
        o.x = f2bf(x.x); o.y = f2bf(x.y); o.z = f2bf(x.z); o.w = f2bf(x.w);
        *(ushort4*)&T[j][dseg * 4] = o;
    }
    __syncthreads();
#pragma unroll
    for (int i = 0; i < 4; i++) {
        int lin = t + i * 256;
        int d = lin >> 4;
        int jseg = lin & 15;
        ushort4 o;
        o.x = T[jseg * 4 + 0][d];
        o.y = T[jseg * 4 + 1][d];
        o.z = T[jseg * 4 + 2][d];
        o.w = T[jseg * 4 + 3][d];
        *(ushort4*)(vtb + (size_t)(d0 + d) * SEQ + j0 + jseg * 4) = o;
    }
}

// C[m][n] = sum_k A[m][k] * B[n][k]  (both operands row-major over k — "B^T input" GEMM)
// 128x128 block tile, BK=32, 256 threads = 4 waves, each wave 64x64 via 4x4 MFMAs.
// A_F32: A is fp32 (W matrix re-read from d_out), converted to bf16 at staging.
template <bool A_F32>
__global__ __launch_bounds__(256) void gemm_tile_kernel(
    const void* __restrict__ Av, const unsigned short* __restrict__ B,
    float* __restrict__ C, int lda, int ldb, int ldc, int K,
    long long strideA, long long strideB, long long strideC) {
    // +8 pad (40 ushorts = 80 B row stride): ds_read_b128 frag reads land 2-way (free)
    __shared__ __align__(16) unsigned short As[128][40];
    __shared__ __align__(16) unsigned short Bs[128][40];

    int b = blockIdx.z;
    int m0 = blockIdx.y * 128;
    int n0 = blockIdx.x * 128;
    const unsigned short* Ab = nullptr;
    const float* Af = nullptr;
    if constexpr (A_F32)
        Af = (const float*)Av + (size_t)b * strideA;
    else
        Ab = (const unsigned short*)Av + (size_t)b * strideA;
    const unsigned short* Bb = B + (size_t)b * strideB;
    float* Cb = C + (size_t)b * strideC;

    int tid = threadIdx.x;
    int wave = tid >> 6, lane = tid & 63;
    int wr = wave >> 1, wc = wave & 1;
    int quad = lane >> 4, l16 = lane & 15;

    f32x4 acc[4][4] = {};

    for (int k0 = 0; k0 < K; k0 += 32) {
        __syncthreads();  // protect previous iteration's frag reads
        if constexpr (A_F32) {
#pragma unroll
            for (int i = 0; i < 4; i++) {
                int lin = tid + i * 256;  // 1024 float4 segments: 128 rows x 8
                int row = lin >> 3;
                int seg = lin & 7;
                float4 x = *(const float4*)(Af + (size_t)(m0 + row) * lda + k0 + seg * 4);
                ushort4 o;
                o.x = f2bf(x.x); o.y = f2bf(x.y); o.z = f2bf(x.z); o.w = f2bf(x.w);
                *(ushort4*)&As[row][seg * 4] = o;
            }
        } else {
#pragma unroll
            for (int i = 0; i < 2; i++) {
                int lin = tid + i * 256;  // 512 16B segments: 128 rows x 4
                int row = lin >> 2;
                int seg = lin & 3;
                *(int4*)&As[row][seg * 8] =
                    *(const int4*)(Ab + (size_t)(m0 + row) * lda + k0 + seg * 8);
            }
        }
#pragma unroll
        for (int i = 0; i < 2; i++) {
            int lin = tid + i * 256;
            int row = lin >> 2;
            int seg = lin & 3;
            *(int4*)&Bs[row][seg * 8] =
                *(const int4*)(Bb + (size_t)(n0 + row) * ldb + k0 + seg * 8);
        }
        __syncthreads();

        bf16x8 afr[4], bfr[4];
#pragma unroll
        for (int mt = 0; mt < 4; mt++)
            afr[mt] = ld_bf16x8(&As[wr * 64 + mt * 16 + l16][quad * 8]);
#pragma unroll
        for (int nt = 0; nt < 4; nt++)
            bfr[nt] = ld_bf16x8(&Bs[wc * 64 + nt * 16 + l16][quad * 8]);
#pragma unroll
        for (int mt = 0; mt < 4; mt++)
#pragma unroll
            for (int nt = 0; nt < 4; nt++)
                acc[mt][nt] = __builtin_amdgcn_mfma_f32_16x16x32_bf16(
                    afr[mt], bfr[nt], acc[mt][nt], 0, 0, 0);
    }

    // C/D layout (m89/m91 verified): col = lane&15, row = quad*4 + reg
#pragma unroll
    for (int mt = 0; mt < 4; mt++) {
#pragma unroll
        for (int nt = 0; nt < 4; nt++) {
            int row = m0 + wr * 64 + mt * 16 + quad * 4;
            int col = n0 + wc * 64 + nt * 16 + l16;
#pragma unroll
            for (int r = 0; r < 4; r++)
                Cb[(size_t)(row + r) * ldc + col] = acc[mt][nt][r];
        }
    }
}

extern "C" void kernel_launch(void* const* d_in, const int* in_sizes, int n_in,
                              void* d_out, int out_size, void* d_ws, size_t ws_size,
                              hipStream_t stream) {
    const float* q = (const float*)d_in[0];
    const float* k = (const float*)d_in[1];
    const float* v = (const float*)d_in[2];

    const size_t elems = (size_t)NBATCH * SEQ * EMB;  // 16,777,216
    unsigned short* Qn = (unsigned short*)d_ws;       // 33.5 MB
    unsigned short* Kn = Qn + elems;                  // 33.5 MB
    unsigned short* Vt = Kn + elems;                  // 33.5 MB (total ws: ~100.7 MB)

    float* O = (float*)d_out;   // [4,4096,1024]
    float* W = O + elems;       // [4,4096,4096]

    norm_rows_kernel<<<NBATCH * SEQ, 256, 0, stream>>>(q, Qn);
    norm_rows_kernel<<<NBATCH * SEQ, 256, 0, stream>>>(k, Kn);
    transpose_v_kernel<<<dim3(SEQ / 64, EMB / 64, NBATCH), 256, 0, stream>>>(v, Vt);

    // GEMM1: W[i][j] = sum_d Qn[i][d] Kn[j][d]   (M=N=4096, K=1024)
    gemm_tile_kernel<false><<<dim3(SEQ / 128, SEQ / 128, NBATCH), 256, 0, stream>>>(
        Qn, Kn, W, EMB, EMB, SEQ, EMB,
        (long long)SEQ * EMB, (long long)SEQ * EMB, (long long)SEQ * SEQ);

    // GEMM2: O[i][d] = sum_j W[i][j] Vt[d][j]    (M=4096, N=1024, K=4096)
    gemm_tile_kernel<true><<<dim3(EMB / 128, SEQ / 128, NBATCH), 256, 0, stream>>>(
        W, Vt, O, SEQ, SEQ, EMB, SEQ,
        (long long)SEQ * SEQ, (long long)EMB * SEQ, (long long)SEQ * EMB);
}

// Round 2
// 877.219 us; speedup vs baseline: 1.1267x; 1.1267x over previous
//
#include <hip/hip_runtime.h>

// SimplifiedAttention on MI355X (gfx950)
//   Qn = l2norm(q, dim=-1); Kn = l2norm(k, dim=-1)
//   W  = Qn @ Kn^T   [4, 4096, 4096]  (output 1)
//   O  = W  @ v      [4, 4096, 1024]  (output 0)
// d_out = [O | W] fp32. bf16 MFMA (no fp32 MFMA on CDNA4).
// R2: global_load_lds width=16 staging for both GEMMs (m97 structure);
//     GEMM1 epilogue dual-writes W fp32 (d_out) + bf16 (ws) so GEMM2's A is DMA-stageable.

#define SEQ 4096
#define EMB 1024
#define NBATCH 4

typedef __attribute__((ext_vector_type(8))) __bf16 bf16x8;
typedef __attribute__((ext_vector_type(4))) float f32x4;
typedef const __attribute__((address_space(1))) void* gas_ptr;
typedef __attribute__((address_space(3))) void* las_ptr;

__device__ __forceinline__ void gld_lds16(const void* g, void* l) {
    // async global->LDS DMA, 16 B/lane. LDS dest is wave-uniform base + lane*16:
    // callers MUST pass lane-contiguous chunk indices within each wave.
    __builtin_amdgcn_global_load_lds((gas_ptr)g, (las_ptr)l, 16, 0, 0);
}

__device__ __forceinline__ unsigned short f2bf(float f) {
    unsigned int u = __builtin_bit_cast(unsigned int, f);
    u += 0x7FFFu + ((u >> 16) & 1u);
    return (unsigned short)(u >> 16);
}

__device__ __forceinline__ bf16x8 ld_bf16x8(const unsigned short* p) {
    int4 v = *(const int4*)p;  // ds_read_b128
    return __builtin_bit_cast(bf16x8, v);
}

// One block (256 threads) per row of 1024 floats: L2-normalize, store bf16.
__global__ __launch_bounds__(256) void norm_rows_kernel(const float* __restrict__ src,
                                                        unsigned short* __restrict__ dst) {
    int row = blockIdx.x;
    int t = threadIdx.x;
    float4 v = *(const float4*)(src + (size_t)row * EMB + t * 4);
    float ss = v.x * v.x + v.y * v.y + v.z * v.z + v.w * v.w;
#pragma unroll
    for (int off = 32; off > 0; off >>= 1) ss += __shfl_down(ss, off, 64);
    __shared__ float red[4];
    if ((t & 63) == 0) red[t >> 6] = ss;
    __syncthreads();
    float tot = red[0] + red[1] + red[2] + red[3];
    float scale = 1.0f / fmaxf(sqrtf(tot), 1e-12f);  // F.normalize eps
    ushort4 o;
    o.x = f2bf(v.x * scale);
    o.y = f2bf(v.y * scale);
    o.z = f2bf(v.z * scale);
    o.w = f2bf(v.w * scale);
    *(ushort4*)(dst + (size_t)row * EMB + t * 4) = o;
}

// V [b][j][d] fp32 -> Vt [b][d][j] bf16, 64x64 LDS tiles, coalesced both sides.
__global__ __launch_bounds__(256) void transpose_v_kernel(const float* __restrict__ v,
                                                          unsigned short* __restrict__ vt) {
    __shared__ __align__(16) unsigned short T[64][68];
    int b = blockIdx.z;
    int j0 = blockIdx.x * 64;
    int d0 = blockIdx.y * 64;
    const float* vb = v + (size_t)b * SEQ * EMB;
    unsigned short* vtb = vt + (size_t)b * (size_t)EMB * SEQ;
    int t = threadIdx.x;
#pragma unroll
    for (int i = 0; i < 4; i++) {
        int lin = t + i * 256;
        int j = lin >> 4;
        int dseg = lin & 15;
        float4 x = *(const float4*)(vb + (size_t)(j0 + j) * EMB + d0 + dseg * 4);
        ushort4 o;
        o.x = f2bf(x.x); o.y = f2bf(x.y); o.z = f2bf(x.z); o.w = f2bf(x.w);
        *(ushort4*)&T[j][dseg * 4] = o;
    }
    __syncthreads();
#pragma unroll
    for (int i = 0; i < 4; i++) {
        int lin = t + i * 256;
        int d = lin >> 4;
        int jseg = lin & 15;
        ushort4 o;
        o.x = T[jseg * 4 + 0][d];
        o.y = T[jseg * 4 + 1][d];
        o.z = T[jseg * 4 + 2][d];
        o.w = T[jseg * 4 + 3][d];
        *(ushort4*)(vtb + (size_t)(d0 + d) * SEQ + j0 + jseg * 4) = o;
    }
}

// C[m][n] = sum_k A[m][k] * B[n][k]  (both operands row-major over k)
// 128x128 tile, BK=32, 256 threads = 4 waves, 4x4 16x16x32 bf16 MFMAs per wave.
// AMODE 0: A bf16, staged via global_load_lds (m97 path)
// AMODE 1: A fp32, converted through VGPRs (fallback if ws too small)
// WBF16:   epilogue dual-writes C as fp32 (C) and bf16 (Cb16)
template <int AMODE, bool WBF16>
__global__ __launch_bounds__(256) void gemm_tile_kernel(
    const void* __restrict__ Av, const unsigned short* __restrict__ B,
    float* __restrict__ C, unsigned short* __restrict__ Cb16,
    int lda, int ldb, int ldc, int K,
    long long strideA, long long strideB, long long strideC) {
    // UNPADDED: global_load_lds lands lane-contiguous 16B chunks; row stride = 64 B.
    __shared__ __align__(16) unsigned short As[128][32];
    __shared__ __align__(16) unsigned short Bs[128][32];

    int b = blockIdx.z;
    int m0 = blockIdx.y * 128;
    int n0 = blockIdx.x * 128;
    const unsigned short* Ab = nullptr;
    const float* Af = nullptr;
    if constexpr (AMODE == 1)
        Af = (const float*)Av + (size_t)b * strideA;
    else
        Ab = (const unsigned short*)Av + (size_t)b * strideA;
    const unsigned short* Bb = B + (size_t)b * strideB;
    float* Cb = C + (size_t)b * strideC;
    unsigned short* Cb16b = WBF16 ? Cb16 + (size_t)b * strideC : nullptr;

    int tid = threadIdx.x;
    int wave = tid >> 6, lane = tid & 63;
    int wr = wave >> 1, wc = wave & 1;
    int quad = lane >> 4, l16 = lane & 15;

    f32x4 acc[4][4] = {};

    for (int k0 = 0; k0 < K; k0 += 32) {
        __syncthreads();  // protect previous iteration's frag reads
        if constexpr (AMODE == 0) {
            // 128 rows x 64 B = 512 16B chunks; chunk c: row = c>>2, seg = c&3.
            // c = tid + i*256 keeps lanes contiguous within each wave (DMA constraint).
#pragma unroll
            for (int i = 0; i < 2; i++) {
                int c = tid + i * 256;
                int row = c >> 2, seg = c & 3;
                gld_lds16(Ab + (size_t)(m0 + row) * lda + k0 + seg * 8,
                          (unsigned short*)As + c * 8);
            }
        } else {
#pragma unroll
            for (int i = 0; i < 4; i++) {
                int lin = tid + i * 256;  // 1024 float4 segs: 128 rows x 8
                int row = lin >> 3;
                int seg = lin & 7;
                float4 x = *(const float4*)(Af + (size_t)(m0 + row) * lda + k0 + seg * 4);
                ushort4 o;
                o.x = f2bf(x.x); o.y = f2bf(x.y); o.z = f2bf(x.z); o.w = f2bf(x.w);
                *(ushort4*)&As[row][seg * 4] = o;
            }
        }
#pragma unroll
        for (int i = 0; i < 2; i++) {
            int c = tid + i * 256;
            int row = c >> 2, seg = c & 3;
            gld_lds16(Bb + (size_t)(n0 + row) * ldb + k0 + seg * 8,
                      (unsigned short*)Bs + c * 8);
        }
        __syncthreads();  // compiler emits vmcnt(0) drain: DMA complete

        bf16x8 afr[4], bfr[4];
#pragma unroll
        for (int mt = 0; mt < 4; mt++)
            afr[mt] = ld_bf16x8(&As[wr * 64 + mt * 16 + l16][quad * 8]);
#pragma unroll
        for (int nt = 0; nt < 4; nt++)
            bfr[nt] = ld_bf16x8(&Bs[wc * 64 + nt * 16 + l16][quad * 8]);
#pragma unroll
        for (int mt = 0; mt < 4; mt++)
#pragma unroll
            for (int nt = 0; nt < 4; nt++)
                acc[mt][nt] = __builtin_amdgcn_mfma_f32_16x16x32_bf16(
                    afr[mt], bfr[nt], acc[mt][nt], 0, 0, 0);
    }

    // C/D layout (m89/m91 verified): col = lane&15, row = quad*4 + reg
#pragma unroll
    for (int mt = 0; mt < 4; mt++) {
#pragma unroll
        for (int nt = 0; nt < 4; nt++) {
            int row = m0 + wr * 64 + mt * 16 + quad * 4;
            int col = n0 + wc * 64 + nt * 16 + l16;
#pragma unroll
            for (int r = 0; r < 4; r++) {
                float val = acc[mt][nt][r];
                Cb[(size_t)(row + r) * ldc + col] = val;
                if constexpr (WBF16)
                    Cb16b[(size_t)(row + r) * ldc + col] = f2bf(val);
            }
        }
    }
}

extern "C" void kernel_launch(void* const* d_in, const int* in_sizes, int n_in,
                              void* d_out, int out_size, void* d_ws, size_t ws_size,
                              hipStream_t stream) {
    const float* q = (const float*)d_in[0];
    const float* k = (const float*)d_in[1];
    const float* v = (const float*)d_in[2];

    const size_t elems = (size_t)NBATCH * SEQ * EMB;   // 16,777,216
    const size_t welems = (size_t)NBATCH * SEQ * SEQ;  // 67,108,864
    unsigned short* Qn = (unsigned short*)d_ws;        // 33.5 MB
    unsigned short* Kn = Qn + elems;                   // 33.5 MB
    unsigned short* Vt = Kn + elems;                   // 33.5 MB
    unsigned short* Wb = Vt + elems;                   // 134.2 MB (bf16 copy of W)
    const size_t ws_needed = (3 * elems + welems) * sizeof(unsigned short);
    const bool fast = ws_size >= ws_needed;

    float* O = (float*)d_out;   // [4,4096,1024]
    float* W = O + elems;       // [4,4096,4096]

    norm_rows_kernel<<<NBATCH * SEQ, 256, 0, stream>>>(q, Qn);
    norm_rows_kernel<<<NBATCH * SEQ, 256, 0, stream>>>(k, Kn);
    transpose_v_kernel<<<dim3(SEQ / 64, EMB / 64, NBATCH), 256, 0, stream>>>(v, Vt);

    // GEMM1: W[i][j] = sum_d Qn[i][d] Kn[j][d]   (M=N=4096, K=1024)
    if (fast) {
        gemm_tile_kernel<0, true><<<dim3(SEQ / 128, SEQ / 128, NBATCH), 256, 0, stream>>>(
            Qn, Kn, W, Wb, EMB, EMB, SEQ, EMB,
            (long long)SEQ * EMB, (long long)SEQ * EMB, (long long)SEQ * SEQ);
        // GEMM2: O[i][d] = sum_j Wb[i][j] Vt[d][j]  (M=4096, N=1024, K=4096)
        gemm_tile_kernel<0, false><<<dim3(EMB / 128, SEQ / 128, NBATCH), 256, 0, stream>>>(
            Wb, Vt, O, nullptr, SEQ, SEQ, EMB, SEQ,
            (long long)SEQ * SEQ, (long long)EMB * SEQ, (long long)SEQ * EMB);
    } else {
        gemm_tile_kernel<0, false><<<dim3(SEQ / 128, SEQ / 128, NBATCH), 256, 0, stream>>>(
            Qn, Kn, W, nullptr, EMB, EMB, SEQ, EMB,
            (long long)SEQ * EMB, (long long)SEQ * EMB, (long long)SEQ * SEQ);
        gemm_tile_kernel<1, false><<<dim3(EMB / 128, SEQ / 128, NBATCH), 256, 0, stream>>>(
            W, Vt, O, nullptr, SEQ, SEQ, EMB, SEQ,
            (long long)SEQ * SEQ, (long long)EMB * SEQ, (long long)SEQ * EMB);
    }
}